// Round 13
// baseline (92.771 us; speedup 1.0000x reference)
//
#include <hip/hip_runtime.h>
#include <hip/hip_fp16.h>

#define CC 256
#define HH 200
#define WW 304
#define PHW 49    // 7*7
#define NCHUNK 4  // channel chunks
#define CHC 64    // channels per chunk
#define SSTR 65   // gather stage row stride (floats)
#define TXT 64    // transpose x-tile
#define TSTR 66   // transpose LDS row stride (floats)

struct Interp { int lo, hi; float w0, w1; };

__device__ __forceinline__ Interp axis_interp(float coord, int size) {
  float valid = (coord >= -1.0f && coord <= (float)size) ? 1.0f : 0.0f;
  float c = fminf(fmaxf(coord, 0.0f), (float)(size - 1));
  float fl = floorf(c);
  int lo = (int)fl;
  int hi = min(lo + 1, size - 1);
  float fr = c - fl;
  Interp r;
  r.lo = lo; r.hi = hi;
  r.w0 = (1.0f - fr) * valid;
  r.w1 = fr * valid;
  return r;
}

// Transpose + hidden ROI sort. Grid (6, B*HH, NCHUNK), 256 thr.
// Blocks x<5: NCHW fp32 -> chunked NHWC fp16, 256B-contiguous channel-row reads.
// Block (5,0,0): deterministic stable ballot bucket-sort of ROIs (4 keys/thread),
// hidden under the ~31us transpose. Other x==5 blocks exit immediately.
__global__ __launch_bounds__(256) void k_transpose_sort(const float* __restrict__ src,
                                                        __half* __restrict__ dst,
                                                        const float* __restrict__ rois,
                                                        int* __restrict__ perm,
                                                        int K, int Bp) {
  __shared__ float tile[TXT][TSTR];
  __shared__ int whist[16][32];
  __shared__ int keytot[32];
  __shared__ int keybase[32];
  int tid = threadIdx.x;

  if (blockIdx.x == 5) {               // ---- sort path ----
    if (blockIdx.y != 0 || blockIdx.z != 0) return;
    int wave = tid >> 6, lane = tid & 63;
    ((int*)whist)[tid] = 0;
    ((int*)whist)[tid + 256] = 0;
    int mykey[4], myrank[4];
#pragma unroll
    for (int kk = 0; kk < 4; ++kk) {   // key g = 64*(wave+4kk) + lane
      int g = tid + 256 * kk;
      int key = 63;                    // inactive sentinel (bit5 set)
      if (g < K) {
        const float* r = rois + (size_t)g * 5;
        int b = (int)r[0];
        float cx = (r[1] + r[3]) * 0.125f;
        float cy = (r[2] + r[4]) * 0.125f;
        int rx = (int)(cx * (8.0f / (float)WW)); rx = max(0, min(7, rx));
        int ry = cy >= (float)(HH / 2) ? 1 : 0;
        key = (((b & 1) * 2 + ry) * 8 + rx) & 31;
      }
      mykey[kk] = key;
    }
    __syncthreads();
#pragma unroll
    for (int kk = 0; kk < 4; ++kk) {   // wave w ballots 64-key group w+4kk
      int key = mykey[kk];
      int g = tid + 256 * kk;
      unsigned long long m = ~0ull;
#pragma unroll
      for (int bit = 0; bit < 6; ++bit) {
        unsigned long long bb = __ballot((key >> bit) & 1);
        m &= ((key >> bit) & 1) ? bb : ~bb;
      }
      unsigned long long below = m & ((1ull << lane) - 1ull);
      myrank[kk] = __popcll(below);
      if (g < K && below == 0ull) whist[wave + 4 * kk][key] = __popcll(m);
    }
    __syncthreads();
    if (tid < 32) {
      int total = 0;
      for (int w = 0; w < 16; ++w) {
        int t = whist[w][tid];
        whist[w][tid] = total;         // exclusive prefix within bucket
        total += t;
      }
      keytot[tid] = total;
    }
    __syncthreads();
    if (tid == 0) {
      int base = 0;
      for (int k2 = 0; k2 < 32; ++k2) { keybase[k2] = base; base += keytot[k2]; }
    }
    __syncthreads();
#pragma unroll
    for (int kk = 0; kk < 4; ++kk) {
      int g = tid + 256 * kk;
      if (g < K)
        perm[keybase[mykey[kk]] + whist[wave + 4 * kk][mykey[kk]] + myrank[kk]] = g;
    }
    return;
  }

  // ---- transpose path ----
  int xq = blockIdx.x;                 // 0..4
  int plane = blockIdx.y;              // b*HH + y
  int chunk = blockIdx.z;              // 0..3
  int b = plane / HH;
  int y = plane - b * HH;
  int x0 = xq * TXT;
  int xlen = min(TXT, WW - x0);        // 64 or 48 (xq==4)
  const float* sp = src + ((size_t)b * CC + chunk * CHC) * (HH * WW) +
                    (size_t)y * WW + x0;
  int ch = tid >> 2;                   // 0..63
  int xb = (tid & 3) * 4;              // 0,4,8,12
  const float* srow = sp + (size_t)ch * (HH * WW);
#pragma unroll
  for (int i = 0; i < 4; ++i) {
    int x = xb + i * 16;
    if (x < xlen) {
      float4 v = *(const float4*)(srow + x);
      tile[x + 0][ch] = v.x;
      tile[x + 1][ch] = v.y;
      tile[x + 2][ch] = v.z;
      tile[x + 3][ch] = v.w;
    }
  }
  __syncthreads();
  __half* dp = dst + (((size_t)chunk * Bp + b) * (size_t)(HH * WW) +
                      (size_t)y * WW + x0) * CHC;
  int xr = tid >> 3;                   // 0..31
  int c8 = (tid & 7) * 8;              // 0..56
#pragma unroll
  for (int pass = 0; pass < 2; ++pass) {
    int x = xr + pass * 32;
    if (x < xlen) {
      const float* trow = &tile[x][c8];
      union { uint4 u; __half2 h[4]; } pk;
      pk.h[0] = __floats2half2_rn(trow[0], trow[1]);
      pk.h[1] = __floats2half2_rn(trow[2], trow[3]);
      pk.h[2] = __floats2half2_rn(trow[4], trow[5]);
      pk.h[3] = __floats2half2_rn(trow[6], trow[7]);
      *(uint4*)(dp + (size_t)x * CHC + c8) = pk.u;
    }
  }
}

// Gather: line-request-bound (~43us); nt loads skip L1 allocation (no reuse).
__global__ __launch_bounds__(512, 8) void k_gather(const __half* __restrict__ feat,
                                                   const float* __restrict__ rois,
                                                   const int* __restrict__ perm,
                                                   float* __restrict__ out,
                                                   int K, int Bp) {
  __shared__ float stage[PHW][SSTR];
  __shared__ int   xoff[14][2];
  __shared__ float xwgt[14][2];
  __shared__ int2  yoff[14];
  __shared__ float2 ywgt[14];
  int q = gridDim.x >> 3;
  int bx = blockIdx.x;
  int slot = (bx & 7) * q + (bx >> 3);
  if (slot >= K) return;
  int k = perm[slot];
  int chunk = blockIdx.y;

  const float* r = rois + (size_t)k * 5;
  int b = __builtin_amdgcn_readfirstlane((int)r[0]);
  float x1 = r[1] * 0.25f, y1 = r[2] * 0.25f;
  float x2 = r[3] * 0.25f, y2 = r[4] * 0.25f;
  float bin_w = fmaxf(x2 - x1, 1.0f) * (1.0f / 7.0f);
  float bin_h = fmaxf(y2 - y1, 1.0f) * (1.0f / 7.0f);

  int tid = threadIdx.x;
  if (tid < 32) {
    int axis = tid >> 4;
    int j = tid & 15;
    if (j < 14) {
      float start = axis ? y1 : x1;
      float binsz = axis ? bin_h : bin_w;
      int size = axis ? HH : WW;
      float coord = start + ((float)j + 0.5f) * 0.5f * binsz;
      Interp ii = axis_interp(coord, size);
      if (axis) {
        yoff[j] = make_int2(ii.lo * (WW * CHC * 2), ii.hi * (WW * CHC * 2));
        ywgt[j] = make_float2(ii.w0, ii.w1);
      } else {
        xoff[j][0] = ii.lo * (CHC * 2);
        xoff[j][1] = ii.hi * (CHC * 2);
        xwgt[j][0] = ii.w0 * 0.25f;
        xwgt[j][1] = ii.w1 * 0.25f;
      }
    }
  }
  __syncthreads();

  int wave = tid >> 6;
  int lane = tid & 63;
  int xsel = lane >> 5;
  int cq = lane & 31;
  const char* fb = (const char*)(feat +
      ((size_t)chunk * Bp + b) * (size_t)(HH * WW) * CHC);
  int laneByte = cq * 4;

  for (int p = wave; p < PHW; p += 8) {
    int ph = p / 7;
    int pw = p - ph * 7;
    int jx0 = 2 * pw, jy0 = 2 * ph;
    int2 yo0 = yoff[jy0], yo1 = yoff[jy0 + 1];
    float2 yw0 = ywgt[jy0], yw1 = ywgt[jy0 + 1];
    __half2 w00 = __float2half2_rn(yw0.x), w01 = __float2half2_rn(yw0.y);
    __half2 w10 = __float2half2_rn(yw1.x), w11 = __float2half2_rn(yw1.y);
    float ax = 0.f, ay = 0.f;
#pragma unroll
    for (int sx = 0; sx < 2; ++sx) {
      int xo = xoff[jx0 + sx][xsel] + laneByte;
      float wx = xwgt[jx0 + sx][xsel];
#pragma unroll
      for (int sy = 0; sy < 2; ++sy) {
        const __half2 wlo = sy ? w10 : w00;
        const __half2 whi = sy ? w11 : w01;
        int2 yo = sy ? yo1 : yo0;
        int i0 = __builtin_nontemporal_load((const int*)(fb + (yo.x + xo)));
        int i1 = __builtin_nontemporal_load((const int*)(fb + (yo.y + xo)));
        __half2 t = __hfma2(*(__half2*)&i1, whi, __hmul2(*(__half2*)&i0, wlo));
        float2 f = __half22float2(t);
        ax += wx * f.x;
        ay += wx * f.y;
      }
    }
    ax += __shfl_xor(ax, 32);
    ay += __shfl_xor(ay, 32);
    if (lane < 32) {
      stage[p][cq * 2 + 0] = ax;
      stage[p][cq * 2 + 1] = ay;
    }
  }
  __syncthreads();

  float* outk = out + (size_t)k * CC * PHW + (size_t)chunk * CHC * PHW;
  for (int i = tid; i < CHC * PHW; i += 512) {
    int cc = i / PHW;
    int p = i - cc * PHW;
    outk[i] = stage[p][cc];
  }
}

// Fallback if workspace too small: one thread per output element, NCHW fp32.
__global__ __launch_bounds__(256) void k_roialign_direct(const float* __restrict__ fe,
                                                         const float* __restrict__ rois,
                                                         float* __restrict__ out,
                                                         int total) {
  int idx = blockIdx.x * 256 + threadIdx.x;
  if (idx >= total) return;
  int pw = idx % 7;
  int t = idx / 7;
  int ph = t % 7; t /= 7;
  int c = t % CC;
  int k = t / CC;
  const float* r = rois + (size_t)k * 5;
  int b = (int)r[0];
  float x1 = r[1] * 0.25f, y1 = r[2] * 0.25f;
  float x2 = r[3] * 0.25f, y2 = r[4] * 0.25f;
  float bin_w = fmaxf(x2 - x1, 1.0f) * (1.0f / 7.0f);
  float bin_h = fmaxf(y2 - y1, 1.0f) * (1.0f / 7.0f);
  const float* base = fe + ((size_t)b * CC + c) * HH * WW;
  float acc = 0.f;
#pragma unroll
  for (int sy = 0; sy < 2; ++sy) {
    float yy = y1 + ((float)(2 * ph + sy) + 0.5f) * 0.5f * bin_h;
    Interp iy = axis_interp(yy, HH);
#pragma unroll
    for (int sx = 0; sx < 2; ++sx) {
      float xx = x1 + ((float)(2 * pw + sx) + 0.5f) * 0.5f * bin_w;
      Interp ix = axis_interp(xx, WW);
      float v00 = base[(size_t)iy.lo * WW + ix.lo];
      float v01 = base[(size_t)iy.lo * WW + ix.hi];
      float v10 = base[(size_t)iy.hi * WW + ix.lo];
      float v11 = base[(size_t)iy.hi * WW + ix.hi];
      acc += iy.w0 * ix.w0 * v00 + iy.w0 * ix.w1 * v01 +
             iy.w1 * ix.w0 * v10 + iy.w1 * ix.w1 * v11;
    }
  }
  out[idx] = acc * 0.25f;
}

extern "C" void kernel_launch(void* const* d_in, const int* in_sizes, int n_in,
                              void* d_out, int out_size, void* d_ws, size_t ws_size,
                              hipStream_t stream) {
  const float* features = (const float*)d_in[0];
  const float* rois = (const float*)d_in[1];
  float* out = (float*)d_out;
  int B = in_sizes[0] / (CC * HH * WW);
  int K = in_sizes[1] / 5;
  size_t feat_bytes = (size_t)B * HH * WW * CC * sizeof(__half);
  size_t perm_bytes = (size_t)((K + 7) & ~7) * sizeof(int);
  if (ws_size >= feat_bytes + perm_bytes && K <= 1024) {
    __half* feat16 = (__half*)d_ws;
    int* perm = (int*)((char*)d_ws + feat_bytes);
    dim3 tg(6, B * HH, NCHUNK);        // x<5: transpose; (5,0,0): sort
    k_transpose_sort<<<tg, 256, 0, stream>>>(features, feat16, rois, perm, K, B);
    int q = (K + 7) / 8;
    dim3 gg(8 * q, NCHUNK);
    k_gather<<<gg, 512, 0, stream>>>(feat16, rois, perm, out, K, B);
  } else {
    int total = K * CC * PHW;
    k_roialign_direct<<<(total + 255) / 256, 256, 0, stream>>>(features, rois, out, total);
  }
}

// Round 14
// 73.279 us; speedup vs baseline: 1.2660x; 1.2660x over previous
//
#include <hip/hip_runtime.h>
#include <hip/hip_fp16.h>

#define CC 256
#define HH 200
#define WW 304
#define PHW 49    // 7*7
#define NCHUNK 4  // channel chunks
#define CHC 64    // channels per chunk
#define SSTR 65   // gather stage row stride (floats)
#define TXT 64    // transpose x-tile
#define TSTR 66   // transpose LDS row stride (floats)

struct Interp { int lo, hi; float w0, w1; };

__device__ __forceinline__ Interp axis_interp(float coord, int size) {
  float valid = (coord >= -1.0f && coord <= (float)size) ? 1.0f : 0.0f;
  float c = fminf(fmaxf(coord, 0.0f), (float)(size - 1));
  float fl = floorf(c);
  int lo = (int)fl;
  int hi = min(lo + 1, size - 1);
  float fr = c - fl;
  Interp r;
  r.lo = lo; r.hi = hi;
  r.w0 = (1.0f - fr) * valid;
  r.w1 = fr * valid;
  return r;
}

// Transpose + hidden ROI sort. Grid (6, B*HH, NCHUNK), 256 thr.
// Blocks x<5: NCHW fp32 -> chunked NHWC fp16, 256B-contiguous channel-row reads.
// Block (5,0,0): deterministic stable ballot bucket-sort of ROIs (4 keys/thread),
// hidden under the ~31us transpose. Other x==5 blocks exit immediately.
__global__ __launch_bounds__(256) void k_transpose_sort(const float* __restrict__ src,
                                                        __half* __restrict__ dst,
                                                        const float* __restrict__ rois,
                                                        int* __restrict__ perm,
                                                        int K, int Bp) {
  __shared__ float tile[TXT][TSTR];
  __shared__ int whist[16][32];
  __shared__ int keytot[32];
  __shared__ int keybase[32];
  int tid = threadIdx.x;

  if (blockIdx.x == 5) {               // ---- sort path ----
    if (blockIdx.y != 0 || blockIdx.z != 0) return;
    int wave = tid >> 6, lane = tid & 63;
    ((int*)whist)[tid] = 0;
    ((int*)whist)[tid + 256] = 0;
    int mykey[4], myrank[4];
#pragma unroll
    for (int kk = 0; kk < 4; ++kk) {   // key g = 256*kk + tid
      int g = tid + 256 * kk;
      int key = 63;                    // inactive sentinel (bit5 set)
      if (g < K) {
        const float* r = rois + (size_t)g * 5;
        int b = (int)r[0];
        float cx = (r[1] + r[3]) * 0.125f;
        float cy = (r[2] + r[4]) * 0.125f;
        int rx = (int)(cx * (8.0f / (float)WW)); rx = max(0, min(7, rx));
        int ry = cy >= (float)(HH / 2) ? 1 : 0;
        key = (((b & 1) * 2 + ry) * 8 + rx) & 31;
      }
      mykey[kk] = key;
    }
    __syncthreads();
#pragma unroll
    for (int kk = 0; kk < 4; ++kk) {   // wave w ballots 64-key group w+4kk
      int key = mykey[kk];
      int g = tid + 256 * kk;
      unsigned long long m = ~0ull;
#pragma unroll
      for (int bit = 0; bit < 6; ++bit) {
        unsigned long long bb = __ballot((key >> bit) & 1);
        m &= ((key >> bit) & 1) ? bb : ~bb;
      }
      unsigned long long below = m & ((1ull << lane) - 1ull);
      myrank[kk] = __popcll(below);
      if (g < K && below == 0ull) whist[wave + 4 * kk][key] = __popcll(m);
    }
    __syncthreads();
    if (tid < 32) {
      int total = 0;
      for (int w = 0; w < 16; ++w) {
        int t = whist[w][tid];
        whist[w][tid] = total;         // exclusive prefix within bucket
        total += t;
      }
      keytot[tid] = total;
    }
    __syncthreads();
    if (tid == 0) {
      int base = 0;
      for (int k2 = 0; k2 < 32; ++k2) { keybase[k2] = base; base += keytot[k2]; }
    }
    __syncthreads();
#pragma unroll
    for (int kk = 0; kk < 4; ++kk) {
      int g = tid + 256 * kk;
      if (g < K)
        perm[keybase[mykey[kk]] + whist[wave + 4 * kk][mykey[kk]] + myrank[kk]] = g;
    }
    return;
  }

  // ---- transpose path ----
  int xq = blockIdx.x;                 // 0..4
  int plane = blockIdx.y;              // b*HH + y
  int chunk = blockIdx.z;              // 0..3
  int b = plane / HH;
  int y = plane - b * HH;
  int x0 = xq * TXT;
  int xlen = min(TXT, WW - x0);        // 64 or 48 (xq==4)
  const float* sp = src + ((size_t)b * CC + chunk * CHC) * (HH * WW) +
                    (size_t)y * WW + x0;
  int ch = tid >> 2;                   // 0..63
  int xb = (tid & 3) * 4;              // 0,4,8,12
  const float* srow = sp + (size_t)ch * (HH * WW);
#pragma unroll
  for (int i = 0; i < 4; ++i) {
    int x = xb + i * 16;
    if (x < xlen) {
      float4 v = *(const float4*)(srow + x);
      tile[x + 0][ch] = v.x;
      tile[x + 1][ch] = v.y;
      tile[x + 2][ch] = v.z;
      tile[x + 3][ch] = v.w;
    }
  }
  __syncthreads();
  __half* dp = dst + (((size_t)chunk * Bp + b) * (size_t)(HH * WW) +
                      (size_t)y * WW + x0) * CHC;
  int xr = tid >> 3;                   // 0..31
  int c8 = (tid & 7) * 8;              // 0..56
#pragma unroll
  for (int pass = 0; pass < 2; ++pass) {
    int x = xr + pass * 32;
    if (x < xlen) {
      const float* trow = &tile[x][c8];
      union { uint4 u; __half2 h[4]; } pk;
      pk.h[0] = __floats2half2_rn(trow[0], trow[1]);
      pk.h[1] = __floats2half2_rn(trow[2], trow[3]);
      pk.h[2] = __floats2half2_rn(trow[4], trow[5]);
      pk.h[3] = __floats2half2_rn(trow[6], trow[7]);
      *(uint4*)(dp + (size_t)x * CHC + c8) = pk.u;
    }
  }
}

// Gather (R12 body, plain loads — L2 reuse is the asset; nt loads proven toxic R13).
__global__ __launch_bounds__(512, 8) void k_gather(const __half* __restrict__ feat,
                                                   const float* __restrict__ rois,
                                                   const int* __restrict__ perm,
                                                   float* __restrict__ out,
                                                   int K, int Bp) {
  __shared__ float stage[PHW][SSTR];
  __shared__ int   xoff[14][2];
  __shared__ float xwgt[14][2];
  __shared__ int2  yoff[14];
  __shared__ float2 ywgt[14];
  int q = gridDim.x >> 3;
  int bx = blockIdx.x;
  int slot = (bx & 7) * q + (bx >> 3);
  if (slot >= K) return;
  int k = perm[slot];
  int chunk = blockIdx.y;

  const float* r = rois + (size_t)k * 5;
  int b = __builtin_amdgcn_readfirstlane((int)r[0]);
  float x1 = r[1] * 0.25f, y1 = r[2] * 0.25f;
  float x2 = r[3] * 0.25f, y2 = r[4] * 0.25f;
  float bin_w = fmaxf(x2 - x1, 1.0f) * (1.0f / 7.0f);
  float bin_h = fmaxf(y2 - y1, 1.0f) * (1.0f / 7.0f);

  int tid = threadIdx.x;
  if (tid < 32) {
    int axis = tid >> 4;
    int j = tid & 15;
    if (j < 14) {
      float start = axis ? y1 : x1;
      float binsz = axis ? bin_h : bin_w;
      int size = axis ? HH : WW;
      float coord = start + ((float)j + 0.5f) * 0.5f * binsz;
      Interp ii = axis_interp(coord, size);
      if (axis) {
        yoff[j] = make_int2(ii.lo * (WW * CHC * 2), ii.hi * (WW * CHC * 2));
        ywgt[j] = make_float2(ii.w0, ii.w1);
      } else {
        xoff[j][0] = ii.lo * (CHC * 2);
        xoff[j][1] = ii.hi * (CHC * 2);
        xwgt[j][0] = ii.w0 * 0.25f;
        xwgt[j][1] = ii.w1 * 0.25f;
      }
    }
  }
  __syncthreads();

  int wave = tid >> 6;
  int lane = tid & 63;
  int xsel = lane >> 5;
  int cq = lane & 31;
  const char* fb = (const char*)(feat +
      ((size_t)chunk * Bp + b) * (size_t)(HH * WW) * CHC);
  int laneByte = cq * 4;

  for (int p = wave; p < PHW; p += 8) {
    int ph = p / 7;
    int pw = p - ph * 7;
    int jx0 = 2 * pw, jy0 = 2 * ph;
    int2 yo0 = yoff[jy0], yo1 = yoff[jy0 + 1];
    float2 yw0 = ywgt[jy0], yw1 = ywgt[jy0 + 1];
    __half2 w00 = __float2half2_rn(yw0.x), w01 = __float2half2_rn(yw0.y);
    __half2 w10 = __float2half2_rn(yw1.x), w11 = __float2half2_rn(yw1.y);
    float ax = 0.f, ay = 0.f;
#pragma unroll
    for (int sx = 0; sx < 2; ++sx) {
      int xo = xoff[jx0 + sx][xsel] + laneByte;
      float wx = xwgt[jx0 + sx][xsel];
#pragma unroll
      for (int sy = 0; sy < 2; ++sy) {
        const __half2 wlo = sy ? w10 : w00;
        const __half2 whi = sy ? w11 : w01;
        int2 yo = sy ? yo1 : yo0;
        ushort2 u0 = *(const ushort2*)(fb + (yo.x + xo));
        ushort2 u1 = *(const ushort2*)(fb + (yo.y + xo));
        __half2 t = __hfma2(*(__half2*)&u1, whi, __hmul2(*(__half2*)&u0, wlo));
        float2 f = __half22float2(t);
        ax += wx * f.x;
        ay += wx * f.y;
      }
    }
    ax += __shfl_xor(ax, 32);
    ay += __shfl_xor(ay, 32);
    if (lane < 32) {
      stage[p][cq * 2 + 0] = ax;
      stage[p][cq * 2 + 1] = ay;
    }
  }
  __syncthreads();

  float* outk = out + (size_t)k * CC * PHW + (size_t)chunk * CHC * PHW;
  for (int i = tid; i < CHC * PHW; i += 512) {
    int cc = i / PHW;
    int p = i - cc * PHW;
    outk[i] = stage[p][cc];
  }
}

// Fallback if workspace too small: one thread per output element, NCHW fp32.
__global__ __launch_bounds__(256) void k_roialign_direct(const float* __restrict__ fe,
                                                         const float* __restrict__ rois,
                                                         float* __restrict__ out,
                                                         int total) {
  int idx = blockIdx.x * 256 + threadIdx.x;
  if (idx >= total) return;
  int pw = idx % 7;
  int t = idx / 7;
  int ph = t % 7; t /= 7;
  int c = t % CC;
  int k = t / CC;
  const float* r = rois + (size_t)k * 5;
  int b = (int)r[0];
  float x1 = r[1] * 0.25f, y1 = r[2] * 0.25f;
  float x2 = r[3] * 0.25f, y2 = r[4] * 0.25f;
  float bin_w = fmaxf(x2 - x1, 1.0f) * (1.0f / 7.0f);
  float bin_h = fmaxf(y2 - y1, 1.0f) * (1.0f / 7.0f);
  const float* base = fe + ((size_t)b * CC + c) * HH * WW;
  float acc = 0.f;
#pragma unroll
  for (int sy = 0; sy < 2; ++sy) {
    float yy = y1 + ((float)(2 * ph + sy) + 0.5f) * 0.5f * bin_h;
    Interp iy = axis_interp(yy, HH);
#pragma unroll
    for (int sx = 0; sx < 2; ++sx) {
      float xx = x1 + ((float)(2 * pw + sx) + 0.5f) * 0.5f * bin_w;
      Interp ix = axis_interp(xx, WW);
      float v00 = base[(size_t)iy.lo * WW + ix.lo];
      float v01 = base[(size_t)iy.lo * WW + ix.hi];
      float v10 = base[(size_t)iy.hi * WW + ix.lo];
      float v11 = base[(size_t)iy.hi * WW + ix.hi];
      acc += iy.w0 * ix.w0 * v00 + iy.w0 * ix.w1 * v01 +
             iy.w1 * ix.w0 * v10 + iy.w1 * ix.w1 * v11;
    }
  }
  out[idx] = acc * 0.25f;
}

extern "C" void kernel_launch(void* const* d_in, const int* in_sizes, int n_in,
                              void* d_out, int out_size, void* d_ws, size_t ws_size,
                              hipStream_t stream) {
  const float* features = (const float*)d_in[0];
  const float* rois = (const float*)d_in[1];
  float* out = (float*)d_out;
  int B = in_sizes[0] / (CC * HH * WW);
  int K = in_sizes[1] / 5;
  size_t feat_bytes = (size_t)B * HH * WW * CC * sizeof(__half);
  size_t perm_bytes = (size_t)((K + 7) & ~7) * sizeof(int);
  if (ws_size >= feat_bytes + perm_bytes && K <= 1024) {
    __half* feat16 = (__half*)d_ws;
    int* perm = (int*)((char*)d_ws + feat_bytes);
    dim3 tg(6, B * HH, NCHUNK);        // x<5: transpose; (5,0,0): sort
    k_transpose_sort<<<tg, 256, 0, stream>>>(features, feat16, rois, perm, K, B);
    int q = (K + 7) / 8;
    dim3 gg(8 * q, NCHUNK);
    k_gather<<<gg, 512, 0, stream>>>(feat16, rois, perm, out, K, B);
  } else {
    int total = K * CC * PHW;
    k_roialign_direct<<<(total + 255) / 256, 256, 0, stream>>>(features, rois, out, total);
  }
}